// Round 10
// baseline (151.117 us; speedup 1.0000x reference)
//
#include <hip/hip_runtime.h>

// SuperPixelMeanEmbed: x = X@W.T + b (M=32, N=K=12288), then per-superpixel
// channel means. W = 604 MB f32 read once.
//
// R10: gemm pinned at ~5.2 TB/s across 5 theories. Last structural variable:
// macro stream pattern. Each block now owns 16 FULL W rows (16 x 48 KB
// contiguous); K is internal, 4 waves k-interleaved (wave w: chunks c%4==w)
// with wave-private double-buffered LDS and NO barriers in the main loop --
// 3072 independent streamers, counted vmcnt(8) per wave. Cross-wave reduce
// at the end. Split-K partials gone: x written once (1.5 MB), aggregate
// reads 4x less. X (bf16, 0.75 MB) is read per-block but L2-resident.

#include <hip/hip_bf16.h>

typedef __attribute__((ext_vector_type(8))) short short8;
typedef __attribute__((ext_vector_type(4))) float f32x4;

namespace {
constexpr int BATCH = 32;
constexpr int CH    = 3;
constexpr int HWPIX = 4096;     // 64*64
constexpr int DDIM  = 12288;
constexpr int KDIM  = 12288;
constexpr int NSEG  = 196;

constexpr int ROWS = 16;        // d-rows per block (all waves share them)
constexpr int BK   = 64;        // k per chunk
constexpr int NCH  = KDIM / BK; // 192 chunks; wave w does c = w, w+4, ...
constexpr int PERW = NCH / 4;   // 48 chunks per wave
}

// native packed f32x2 -> bf16x2 (v_cvt_pk_bf16_f32, RNE)
__device__ __forceinline__ unsigned pkbf16(float lo, float hi) {
    __hip_bfloat162 h = __float22bfloat162_rn(make_float2(lo, hi));
    union { __hip_bfloat162 h2; unsigned u; } c; c.h2 = h; return c.u;
}

__device__ __forceinline__ void gload16(const void* g, void* l) {
    __builtin_amdgcn_global_load_lds(
        (const __attribute__((address_space(1))) void*)g,
        (__attribute__((address_space(3))) void*)l, 16, 0, 0);
}

// ---------------- X f32 -> bf16, same [b][k] layout ----------------
__global__ __launch_bounds__(256) void convert_x_kernel(
    const float* __restrict__ X, ushort* __restrict__ Xb)
{
    const int i = (blockIdx.x * 256 + threadIdx.x) * 4;
    const float4 v = *reinterpret_cast<const float4*>(X + i);
    union { unsigned u[2]; ushort4 q; } o;
    o.u[0] = pkbf16(v.x, v.y);
    o.u[1] = pkbf16(v.z, v.w);
    *reinterpret_cast<ushort4*>(Xb + i) = o.q;
}

// ---------------- MFMA skinny GEMM: 16 full rows per block ----------------
// grid = 768; block 256 = 4 waves. All waves compute the same 16(d) x 32(b)
// output over disjoint k-chunks; wave-private LDS double buffers; no main-
// loop barriers. Chunk-XOR involution (slot = chunk ^ (row&7), 16B granules)
// on both staged tiles -> conflict-free ds_read_b128.
__global__ __launch_bounds__(256, 2) void gemm_kernel(
    const float* __restrict__ Wg, const ushort* __restrict__ Xb,
    float* __restrict__ x)
{
    __shared__ float  wl[4][2][ROWS * BK];    // 4 x 2 x 4 KB
    __shared__ ushort xl[4][2][BATCH * BK];   // 4 x 2 x 4 KB
    __shared__ float  red[4][ROWS][BATCH];    // 8 KB   (total 72 KB)

    const int lane = threadIdx.x & 63;
    const int w    = threadIdx.x >> 6;
    const int d0   = blockIdx.x * ROWS;

    f32x4 acc[2];
#pragma unroll
    for (int nt = 0; nt < 2; ++nt) acc[nt] = (f32x4)(0.f);

    // Staging (8 gloads/chunk, wave-private). W: instr i covers rows i*4 +
    // (lane>>4), 16 lanes x 16B = 256 B per row. X: instr i covers b-rows
    // i*8 + (lane>>3), 8 lanes x 16B = 128 B per row.
#define STAGE(buf, c)                                                        \
    {                                                                        \
        const int k0 = (c) * BK;                                             \
        _Pragma("unroll")                                                    \
        for (int i = 0; i < 4; ++i) {                                        \
            const int r  = i * 4 + (lane >> 4);                              \
            const int cs = (lane & 15) ^ (r & 7);                            \
            gload16(Wg + (size_t)(d0 + r) * KDIM + k0 + cs * 4,              \
                    &wl[w][buf][i * 4 * BK]);                                \
        }                                                                    \
        _Pragma("unroll")                                                    \
        for (int i = 0; i < 4; ++i) {                                        \
            const int xr = i * 8 + (lane >> 3);                              \
            const int cs = (lane & 7) ^ (xr & 7);                            \
            gload16(Xb + (size_t)xr * KDIM + k0 + cs * 8,                    \
                    &xl[w][buf][i * 8 * BK]);                                \
        }                                                                    \
    }

#define COMPUTE(buf)                                                         \
    {                                                                        \
        _Pragma("unroll")                                                    \
        for (int kk = 0; kk < 2; ++kk) {                                     \
            const int R  = lane & 15;                                        \
            const int c0 = kk * 8 + (lane >> 4) * 2;  /* 16B chunk idx */    \
            const float4 f0 = *reinterpret_cast<const float4*>(              \
                &wl[w][buf][R * BK + ((c0    ) ^ (R & 7)) * 4]);             \
            const float4 f1 = *reinterpret_cast<const float4*>(              \
                &wl[w][buf][R * BK + ((c0 + 1) ^ (R & 7)) * 4]);             \
            union { unsigned u[4]; short8 s8; } A;                           \
            A.u[0] = pkbf16(f0.x, f0.y);                                     \
            A.u[1] = pkbf16(f0.z, f0.w);                                     \
            A.u[2] = pkbf16(f1.x, f1.y);                                     \
            A.u[3] = pkbf16(f1.z, f1.w);                                     \
            _Pragma("unroll")                                                \
            for (int nt = 0; nt < 2; ++nt) {                                 \
                const int b = nt * 16 + (lane & 15);                         \
                const int s = kk * 4 + (lane >> 4);                          \
                const short8 bb = *reinterpret_cast<const short8*>(          \
                    &xl[w][buf][b * BK + (s ^ (b & 7)) * 8]);                \
                acc[nt] = __builtin_amdgcn_mfma_f32_16x16x32_bf16(           \
                    A.s8, bb, acc[nt], 0, 0, 0);                             \
            }                                                                \
        }                                                                    \
    }

    // wave-private pipeline: chunks w, w+4, ..., two in flight
    STAGE(0, w)
    STAGE(1, w + 4)
    for (int i = 0; i < PERW; ++i) {
        const int cur = i & 1;
        if (i + 1 < PERW) {
            asm volatile("s_waitcnt vmcnt(8)" ::: "memory");   // cur's 8 landed
        } else {
            asm volatile("s_waitcnt vmcnt(0)" ::: "memory");
        }
        __builtin_amdgcn_sched_barrier(0);
        COMPUTE(cur)
        asm volatile("s_waitcnt lgkmcnt(0)" ::: "memory");     // ds_reads done
        __builtin_amdgcn_sched_barrier(0);
        if (i + 2 < PERW) STAGE(cur, w + 4 * (i + 2))          // reuse cur buf
    }
#undef STAGE
#undef COMPUTE

    // cross-wave reduce: 4 partial 16x32 tiles -> x[b][d0..d0+15]
#pragma unroll
    for (int nt = 0; nt < 2; ++nt) {
        const int b  = nt * 16 + (lane & 15);
        const int r0 = (lane >> 4) * 4;
#pragma unroll
        for (int r = 0; r < 4; ++r)
            red[w][r0 + r][b] = acc[nt][r];
    }
    __syncthreads();
#pragma unroll
    for (int h = 0; h < 2; ++h) {
        const int idx = h * 256 + threadIdx.x;   // 0..511
        const int b   = idx >> 4;                // 0..31
        const int r   = idx & 15;                // 0..15
        const float s = red[0][r][b] + red[1][r][b]
                      + red[2][r][b] + red[3][r][b];
        x[(size_t)b * DDIM + d0 + r] = s;
    }
}

// ---------------- segment aggregation: one block per (image, channel) ------
__global__ __launch_bounds__(256) void aggregate_kernel(
    const float* __restrict__ x, const float* __restrict__ bias,
    const int* __restrict__ seg, float* __restrict__ out)
{
    __shared__ float sums[NSEG];
    __shared__ int   hist[NSEG];
    const int b = blockIdx.x / CH;
    const int c = blockIdx.x % CH;
    for (int i = threadIdx.x; i < NSEG; i += 256) { sums[i] = 0.f; hist[i] = 0; }
    __syncthreads();
    const size_t base = (size_t)b * DDIM + c * HWPIX;
#pragma unroll
    for (int it = 0; it < HWPIX / 1024; ++it) {
        const int p0 = it * 1024 + threadIdx.x * 4;
        const int4 s4 = *reinterpret_cast<const int4*>(seg + b * HWPIX + p0);
        float4 v = *reinterpret_cast<const float4*>(bias + c * HWPIX + p0);
        const float4 xv = *reinterpret_cast<const float4*>(x + base + p0);
        v.x += xv.x; v.y += xv.y; v.z += xv.z; v.w += xv.w;
        atomicAdd(&hist[s4.x], 1); atomicAdd(&sums[s4.x], v.x);
        atomicAdd(&hist[s4.y], 1); atomicAdd(&sums[s4.y], v.y);
        atomicAdd(&hist[s4.z], 1); atomicAdd(&sums[s4.z], v.z);
        atomicAdd(&hist[s4.w], 1); atomicAdd(&sums[s4.w], v.w);
    }
    __syncthreads();
    for (int s = threadIdx.x; s < NSEG; s += 256)
        out[(b * NSEG + s) * CH + c] = sums[s] / fmaxf((float)hist[s], 1.f);
}

extern "C" void kernel_launch(void* const* d_in, const int* in_sizes, int n_in,
                              void* d_out, int out_size, void* d_ws, size_t ws_size,
                              hipStream_t stream) {
    const float* X    = (const float*)d_in[0];
    const float* W    = (const float*)d_in[1];
    const float* bias = (const float*)d_in[2];
    const int*   seg  = (const int*)d_in[3];
    float* out = (float*)d_out;

    ushort* Xb = (ushort*)d_ws;                        // [32][12288] bf16, 0.75 MB
    float*  x  = (float*)(Xb + (size_t)BATCH * KDIM);  // [32][12288] f32, 1.5 MB

    convert_x_kernel<<<BATCH * KDIM / (256 * 4), 256, 0, stream>>>(X, Xb);
    gemm_kernel<<<DDIM / ROWS, 256, 0, stream>>>(W, Xb, x);
    aggregate_kernel<<<BATCH * CH, 256, 0, stream>>>(x, bias, seg, out);
}

// Round 11
// 136.527 us; speedup vs baseline: 1.1069x; 1.1069x over previous
//
#include <hip/hip_runtime.h>

// SuperPixelMeanEmbed: x = X@W.T + b (M=32, N=K=12288), then per-superpixel
// channel means. W = 604 MB f32 read once.
//
// R11: gemm reverted to R9 (best: BK=128, KSPLIT=8, counted vmcnt(10)) --
// its ~5.2 TB/s delivered read rate is invariant across 6 structural
// variants = device read-path ceiling. Remaining slack: aggregate's 8192
// LDS atomics/block onto a SHARED 196-slot table (~21-way contention, 96
// blocks, no TLP). Fix: per-wave private sum/cnt rows (4x196), disjoint
// 1024-pixel stripe per wave, cross-wave reduce at the end.

#include <hip/hip_bf16.h>

typedef __attribute__((ext_vector_type(8))) short short8;
typedef __attribute__((ext_vector_type(4))) float f32x4;

namespace {
constexpr int BATCH = 32;
constexpr int CH    = 3;
constexpr int HWPIX = 4096;     // 64*64
constexpr int DDIM  = 12288;
constexpr int KDIM  = 12288;
constexpr int NSEG  = 196;

constexpr int ROWS = 64;        // d-rows per block (wave w owns rows w*16..+15)
constexpr int BK   = 128;       // k per LDS tile (512 B per W row per tile)
}

// native packed f32x2 -> bf16x2 (v_cvt_pk_bf16_f32, RNE)
__device__ __forceinline__ unsigned pkbf16(float lo, float hi) {
    __hip_bfloat162 h = __float22bfloat162_rn(make_float2(lo, hi));
    union { __hip_bfloat162 h2; unsigned u; } c; c.h2 = h; return c.u;
}

__device__ __forceinline__ void gload16(const void* g, void* l) {
    __builtin_amdgcn_global_load_lds(
        (const __attribute__((address_space(1))) void*)g,
        (__attribute__((address_space(3))) void*)l, 16, 0, 0);
}

// ---------------- X f32 -> bf16, same [b][k] layout ----------------
__global__ __launch_bounds__(256) void convert_x_kernel(
    const float* __restrict__ X, ushort* __restrict__ Xb)
{
    const int i = (blockIdx.x * 256 + threadIdx.x) * 4;
    const float4 v = *reinterpret_cast<const float4*>(X + i);
    union { unsigned u[2]; ushort4 q; } o;
    o.u[0] = pkbf16(v.x, v.y);
    o.u[1] = pkbf16(v.z, v.w);
    *reinterpret_cast<ushort4*>(Xb + i) = o.q;
}

// ---------------- MFMA skinny GEMM, split-K (R9 structure) ----------------
// grid = (DDIM/64, KSPLIT); block 256 = 4 waves. Wave w computes the
// 16(d) x 32(batch) output tile for rows d0+w*16..+15 over its k-range.
// LDS: W tile f32 [64r][128k] (32 KB) + X tile bf16 [32b][128k] (8 KB), x2.
// Both staged by global_load_lds with pre-swizzled source chunks
// (16B chunk slot = chunk ^ (row&7)); reads XOR the same -> conflict-free.
template<int KSPLIT>
__global__ __launch_bounds__(256, 2) void gemm_kernel(
    const float* __restrict__ Wg, const ushort* __restrict__ Xb,
    float* __restrict__ xpart)
{
    constexpr int KRANGE = KDIM / KSPLIT;
    constexpr int NTILE  = KRANGE / BK;

    __shared__ float  wl[2][ROWS * BK];    // 2 x 32 KB
    __shared__ ushort xl[2][BATCH * BK];   // 2 x 8 KB

    const int t    = threadIdx.x;
    const int lane = t & 63;
    const int w    = t >> 6;
    const int d0   = blockIdx.x * ROWS;
    const int kb   = blockIdx.y * KRANGE;

    f32x4 acc[2];
#pragma unroll
    for (int nt = 0; nt < 2; ++nt) acc[nt] = (f32x4)(0.f);

#define STAGE(buf, tile)                                                     \
    {                                                                        \
        const int k0 = kb + (tile) * BK;                                     \
        _Pragma("unroll")                                                    \
        for (int i = 0; i < 8; ++i) {                                        \
            const int r  = w * 16 + i * 2 + (lane >> 5);                     \
            const int cs = (lane & 31) ^ (r & 7);                            \
            gload16(Wg + (size_t)(d0 + r) * KDIM + k0 + cs * 4,              \
                    &wl[buf][(w * 16 + i * 2) * BK]);                        \
        }                                                                    \
        _Pragma("unroll")                                                    \
        for (int i = 0; i < 2; ++i) {                                        \
            const int xr = w * 8 + i * 4 + (lane >> 4);                      \
            const int cs = (lane & 15) ^ (xr & 7);                           \
            gload16(Xb + (size_t)xr * KDIM + k0 + cs * 8,                    \
                    &xl[buf][(w * 8 + i * 4) * BK]);                         \
        }                                                                    \
    }

#define COMPUTE(buf)                                                         \
    {                                                                        \
        _Pragma("unroll")                                                    \
        for (int kk = 0; kk < 4; ++kk) {                                     \
            const int R  = w * 16 + (lane & 15);                             \
            const int c0 = kk * 8 + (lane >> 4) * 2;  /* 16B chunk idx */    \
            const float4 f0 = *reinterpret_cast<const float4*>(              \
                &wl[buf][R * BK + (((c0    ) ^ (R & 7)) & 31) * 4]);         \
            const float4 f1 = *reinterpret_cast<const float4*>(              \
                &wl[buf][R * BK + (((c0 + 1) ^ (R & 7)) & 31) * 4]);         \
            union { unsigned u[4]; short8 s8; } A;                           \
            A.u[0] = pkbf16(f0.x, f0.y);                                     \
            A.u[1] = pkbf16(f0.z, f0.w);                                     \
            A.u[2] = pkbf16(f1.x, f1.y);                                     \
            A.u[3] = pkbf16(f1.z, f1.w);                                     \
            _Pragma("unroll")                                                \
            for (int nt = 0; nt < 2; ++nt) {                                 \
                const int b  = nt * 16 + (lane & 15);                        \
                const int xc = (kk * 4 + (lane >> 4)) ^ (b & 7);             \
                const short8 bb = *reinterpret_cast<const short8*>(          \
                    &xl[buf][b * BK + xc * 8]);                              \
                acc[nt] = __builtin_amdgcn_mfma_f32_16x16x32_bf16(           \
                    A.s8, bb, acc[nt], 0, 0, 0);                             \
            }                                                                \
        }                                                                    \
    }

    // prologue: two tiles (2 x 10 instrs/wave) in flight
    STAGE(0, 0)
    STAGE(1, 1)
    for (int tile = 0; tile < NTILE; ++tile) {
        const int cur = tile & 1;
        // wait current tile's 10 loads; keep next tile's 10 in flight
        if (tile + 1 < NTILE) {
            asm volatile("s_waitcnt vmcnt(10)" ::: "memory");
        } else {
            asm volatile("s_waitcnt vmcnt(0)" ::: "memory");
        }
        __builtin_amdgcn_s_barrier();          // all waves' quarters landed
        asm volatile("" ::: "memory");
        COMPUTE(cur)
        asm volatile("s_waitcnt lgkmcnt(0)" ::: "memory");  // LDS reads retired
        __builtin_amdgcn_s_barrier();          // safe to overwrite cur
        asm volatile("" ::: "memory");
        if (tile + 2 < NTILE) STAGE(cur, tile + 2)   // before waiting on t+1
    }
#undef STAGE
#undef COMPUTE

    // epilogue: D layout col=lane&15 (batch), row=(lane>>4)*4+reg (d)
    float* xp = xpart + (size_t)blockIdx.y * BATCH * DDIM;
#pragma unroll
    for (int nt = 0; nt < 2; ++nt) {
        const int b = nt * 16 + (lane & 15);
        const int m = d0 + w * 16 + (lane >> 4) * 4;
#pragma unroll
        for (int r = 0; r < 4; ++r)
            xp[(size_t)b * DDIM + m + r] = acc[nt][r];
    }
}

// ---------------- segment aggregation v2: per-wave private tables ----------
// grid = 96 (image, channel); 4 waves, each owns a disjoint 1024-pixel
// stripe and a private sum/cnt row -> 4x less contention, no cross-wave
// collisions; cross-wave reduce + divide at the end.
template<int KSPLIT>
__global__ __launch_bounds__(256) void aggregate_kernel(
    const float* __restrict__ xpart, const float* __restrict__ bias,
    const int* __restrict__ seg, float* __restrict__ out)
{
    __shared__ float wsum[4][NSEG];
    __shared__ float wcnt[4][NSEG];
    const int b    = blockIdx.x / CH;
    const int c    = blockIdx.x % CH;
    const int t    = threadIdx.x;
    const int w    = t >> 6;
    const int lane = t & 63;
    for (int i = t; i < 4 * NSEG; i += 256) {
        (&wsum[0][0])[i] = 0.f;
        (&wcnt[0][0])[i] = 0.f;
    }
    __syncthreads();
    const size_t base = (size_t)b * DDIM + c * HWPIX;
#pragma unroll
    for (int it = 0; it < 4; ++it) {
        const int p0 = w * 1024 + it * 256 + lane * 4;
        const int4 s4 = *reinterpret_cast<const int4*>(seg + b * HWPIX + p0);
        float4 v = *reinterpret_cast<const float4*>(bias + c * HWPIX + p0);
#pragma unroll
        for (int ks = 0; ks < KSPLIT; ++ks) {
            const float4 xv = *reinterpret_cast<const float4*>(
                xpart + (size_t)ks * BATCH * DDIM + base + p0);
            v.x += xv.x; v.y += xv.y; v.z += xv.z; v.w += xv.w;
        }
        atomicAdd(&wsum[w][s4.x], v.x); atomicAdd(&wcnt[w][s4.x], 1.f);
        atomicAdd(&wsum[w][s4.y], v.y); atomicAdd(&wcnt[w][s4.y], 1.f);
        atomicAdd(&wsum[w][s4.z], v.z); atomicAdd(&wcnt[w][s4.z], 1.f);
        atomicAdd(&wsum[w][s4.w], v.w); atomicAdd(&wcnt[w][s4.w], 1.f);
    }
    __syncthreads();
    for (int s = t; s < NSEG; s += 256) {
        const float sum = wsum[0][s] + wsum[1][s] + wsum[2][s] + wsum[3][s];
        const float cnt = wcnt[0][s] + wcnt[1][s] + wcnt[2][s] + wcnt[3][s];
        out[(b * NSEG + s) * CH + c] = sum / fmaxf(cnt, 1.f);
    }
}

extern "C" void kernel_launch(void* const* d_in, const int* in_sizes, int n_in,
                              void* d_out, int out_size, void* d_ws, size_t ws_size,
                              hipStream_t stream) {
    const float* X    = (const float*)d_in[0];
    const float* W    = (const float*)d_in[1];
    const float* bias = (const float*)d_in[2];
    const int*   seg  = (const int*)d_in[3];
    float* out = (float*)d_out;

    ushort* Xb    = (ushort*)d_ws;                         // [32][12288] bf16, 0.75 MB
    float*  xpart = (float*)(Xb + (size_t)BATCH * KDIM);   // [KSPLIT][32][12288]

    convert_x_kernel<<<BATCH * KDIM / (256 * 4), 256, 0, stream>>>(X, Xb);

    const size_t base_ws = (size_t)BATCH * KDIM * 2;
    const size_t part_ws = (size_t)BATCH * DDIM * 4;
    if (ws_size >= base_ws + 8 * part_ws) {
        dim3 grid(DDIM / ROWS, 8);
        gemm_kernel<8><<<grid, 256, 0, stream>>>(W, Xb, xpart);
        aggregate_kernel<8><<<BATCH * CH, 256, 0, stream>>>(xpart, bias, seg, out);
    } else {
        dim3 grid(DDIM / ROWS, 4);
        gemm_kernel<4><<<grid, 256, 0, stream>>>(W, Xb, xpart);
        aggregate_kernel<4><<<BATCH * CH, 256, 0, stream>>>(xpart, bias, seg, out);
    }
}

// Round 12
// 131.954 us; speedup vs baseline: 1.1452x; 1.0347x over previous
//
#include <hip/hip_runtime.h>

// SuperPixelMeanEmbed: x = X@W.T + b (M=32, N=K=12288), then per-superpixel
// channel means. W = 604 MB f32 read once.
//
// R12 = R9 (best measured: 133.5 us). gemm: MFMA 16x16x32_bf16, W converted
// f32->bf16 in-register (W read once as f32), BK=128, KSPLIT=8, 80 KB LDS
// double-buffer, global_load_lds staging with XOR-involution chunk swizzle,
// counted s_waitcnt vmcnt(10) + raw barriers. Delivered ~5.2 TB/s W read --
// invariant across 6 structural variants (occupancy/BK/sync/KSPLIT/macro
// pattern) => device read-path ceiling for this access class. Aggregate:
// per-(image,channel) block, shared LDS table (R11's private tables: null).

#include <hip/hip_bf16.h>

typedef __attribute__((ext_vector_type(8))) short short8;
typedef __attribute__((ext_vector_type(4))) float f32x4;

namespace {
constexpr int BATCH = 32;
constexpr int CH    = 3;
constexpr int HWPIX = 4096;     // 64*64
constexpr int DDIM  = 12288;
constexpr int KDIM  = 12288;
constexpr int NSEG  = 196;

constexpr int ROWS = 64;        // d-rows per block (wave w owns rows w*16..+15)
constexpr int BK   = 128;       // k per LDS tile (512 B per W row per tile)
}

// native packed f32x2 -> bf16x2 (v_cvt_pk_bf16_f32, RNE)
__device__ __forceinline__ unsigned pkbf16(float lo, float hi) {
    __hip_bfloat162 h = __float22bfloat162_rn(make_float2(lo, hi));
    union { __hip_bfloat162 h2; unsigned u; } c; c.h2 = h; return c.u;
}

__device__ __forceinline__ void gload16(const void* g, void* l) {
    __builtin_amdgcn_global_load_lds(
        (const __attribute__((address_space(1))) void*)g,
        (__attribute__((address_space(3))) void*)l, 16, 0, 0);
}

// ---------------- X f32 -> bf16, same [b][k] layout ----------------
__global__ __launch_bounds__(256) void convert_x_kernel(
    const float* __restrict__ X, ushort* __restrict__ Xb)
{
    const int i = (blockIdx.x * 256 + threadIdx.x) * 4;
    const float4 v = *reinterpret_cast<const float4*>(X + i);
    union { unsigned u[2]; ushort4 q; } o;
    o.u[0] = pkbf16(v.x, v.y);
    o.u[1] = pkbf16(v.z, v.w);
    *reinterpret_cast<ushort4*>(Xb + i) = o.q;
}

// ---------------- MFMA skinny GEMM, split-K ----------------
// grid = (DDIM/64, KSPLIT); block 256 = 4 waves. Wave w computes the
// 16(d) x 32(batch) output tile for rows d0+w*16..+15 over its k-range.
// LDS: W tile f32 [64r][128k] (32 KB) + X tile bf16 [32b][128k] (8 KB), x2.
// Both staged by global_load_lds with pre-swizzled source chunks
// (16B chunk slot = chunk ^ (row&7)); reads XOR the same -> conflict-free
// (residual 2-way aliasing is free).
template<int KSPLIT>
__global__ __launch_bounds__(256, 2) void gemm_kernel(
    const float* __restrict__ Wg, const ushort* __restrict__ Xb,
    float* __restrict__ xpart)
{
    constexpr int KRANGE = KDIM / KSPLIT;
    constexpr int NTILE  = KRANGE / BK;

    __shared__ float  wl[2][ROWS * BK];    // 2 x 32 KB
    __shared__ ushort xl[2][BATCH * BK];   // 2 x 8 KB

    const int t    = threadIdx.x;
    const int lane = t & 63;
    const int w    = t >> 6;
    const int d0   = blockIdx.x * ROWS;
    const int kb   = blockIdx.y * KRANGE;

    f32x4 acc[2];
#pragma unroll
    for (int nt = 0; nt < 2; ++nt) acc[nt] = (f32x4)(0.f);

#define STAGE(buf, tile)                                                     \
    {                                                                        \
        const int k0 = kb + (tile) * BK;                                     \
        _Pragma("unroll")                                                    \
        for (int i = 0; i < 8; ++i) {                                        \
            const int r  = w * 16 + i * 2 + (lane >> 5);                     \
            const int cs = (lane & 31) ^ (r & 7);                            \
            gload16(Wg + (size_t)(d0 + r) * KDIM + k0 + cs * 4,              \
                    &wl[buf][(w * 16 + i * 2) * BK]);                        \
        }                                                                    \
        _Pragma("unroll")                                                    \
        for (int i = 0; i < 2; ++i) {                                        \
            const int xr = w * 8 + i * 4 + (lane >> 4);                      \
            const int cs = (lane & 15) ^ (xr & 7);                           \
            gload16(Xb + (size_t)xr * KDIM + k0 + cs * 8,                    \
                    &xl[buf][(w * 8 + i * 4) * BK]);                         \
        }                                                                    \
    }

#define COMPUTE(buf)                                                         \
    {                                                                        \
        _Pragma("unroll")                                                    \
        for (int kk = 0; kk < 4; ++kk) {                                     \
            const int R  = w * 16 + (lane & 15);                             \
            const int c0 = kk * 8 + (lane >> 4) * 2;  /* 16B chunk idx */    \
            const float4 f0 = *reinterpret_cast<const float4*>(              \
                &wl[buf][R * BK + (((c0    ) ^ (R & 7)) & 31) * 4]);         \
            const float4 f1 = *reinterpret_cast<const float4*>(              \
                &wl[buf][R * BK + (((c0 + 1) ^ (R & 7)) & 31) * 4]);         \
            union { unsigned u[4]; short8 s8; } A;                           \
            A.u[0] = pkbf16(f0.x, f0.y);                                     \
            A.u[1] = pkbf16(f0.z, f0.w);                                     \
            A.u[2] = pkbf16(f1.x, f1.y);                                     \
            A.u[3] = pkbf16(f1.z, f1.w);                                     \
            _Pragma("unroll")                                                \
            for (int nt = 0; nt < 2; ++nt) {                                 \
                const int b  = nt * 16 + (lane & 15);                        \
                const int xc = (kk * 4 + (lane >> 4)) ^ (b & 7);             \
                const short8 bb = *reinterpret_cast<const short8*>(          \
                    &xl[buf][b * BK + xc * 8]);                              \
                acc[nt] = __builtin_amdgcn_mfma_f32_16x16x32_bf16(           \
                    A.s8, bb, acc[nt], 0, 0, 0);                             \
            }                                                                \
        }                                                                    \
    }

    // prologue: two tiles (2 x 10 instrs/wave) in flight
    STAGE(0, 0)
    STAGE(1, 1)
    for (int tile = 0; tile < NTILE; ++tile) {
        const int cur = tile & 1;
        // wait current tile's 10 loads; keep next tile's 10 in flight
        if (tile + 1 < NTILE) {
            asm volatile("s_waitcnt vmcnt(10)" ::: "memory");
        } else {
            asm volatile("s_waitcnt vmcnt(0)" ::: "memory");
        }
        __builtin_amdgcn_s_barrier();          // all waves' quarters landed
        asm volatile("" ::: "memory");
        COMPUTE(cur)
        asm volatile("s_waitcnt lgkmcnt(0)" ::: "memory");  // LDS reads retired
        __builtin_amdgcn_s_barrier();          // safe to overwrite cur
        asm volatile("" ::: "memory");
        if (tile + 2 < NTILE) STAGE(cur, tile + 2)   // before waiting on t+1
    }
#undef STAGE
#undef COMPUTE

    // epilogue: D layout col=lane&15 (batch), row=(lane>>4)*4+reg (d)
    float* xp = xpart + (size_t)blockIdx.y * BATCH * DDIM;
#pragma unroll
    for (int nt = 0; nt < 2; ++nt) {
        const int b = nt * 16 + (lane & 15);
        const int m = d0 + w * 16 + (lane >> 4) * 4;
#pragma unroll
        for (int r = 0; r < 4; ++r)
            xp[(size_t)b * DDIM + m + r] = acc[nt][r];
    }
}

// ---------------- segment aggregation: one block per (image, channel) ------
template<int KSPLIT>
__global__ __launch_bounds__(256) void aggregate_kernel(
    const float* __restrict__ xpart, const float* __restrict__ bias,
    const int* __restrict__ seg, float* __restrict__ out)
{
    __shared__ float sums[NSEG];
    __shared__ int   hist[NSEG];
    const int b = blockIdx.x / CH;
    const int c = blockIdx.x % CH;
    for (int i = threadIdx.x; i < NSEG; i += 256) { sums[i] = 0.f; hist[i] = 0; }
    __syncthreads();
    const size_t base = (size_t)b * DDIM + c * HWPIX;
#pragma unroll
    for (int it = 0; it < HWPIX / 1024; ++it) {
        const int p0 = it * 1024 + threadIdx.x * 4;
        const int4 s4 = *reinterpret_cast<const int4*>(seg + b * HWPIX + p0);
        float4 v = *reinterpret_cast<const float4*>(bias + c * HWPIX + p0);
#pragma unroll
        for (int ks = 0; ks < KSPLIT; ++ks) {
            const float4 xv = *reinterpret_cast<const float4*>(
                xpart + (size_t)ks * BATCH * DDIM + base + p0);
            v.x += xv.x; v.y += xv.y; v.z += xv.z; v.w += xv.w;
        }
        atomicAdd(&hist[s4.x], 1); atomicAdd(&sums[s4.x], v.x);
        atomicAdd(&hist[s4.y], 1); atomicAdd(&sums[s4.y], v.y);
        atomicAdd(&hist[s4.z], 1); atomicAdd(&sums[s4.z], v.z);
        atomicAdd(&hist[s4.w], 1); atomicAdd(&sums[s4.w], v.w);
    }
    __syncthreads();
    for (int s = threadIdx.x; s < NSEG; s += 256)
        out[(b * NSEG + s) * CH + c] = sums[s] / fmaxf((float)hist[s], 1.f);
}

extern "C" void kernel_launch(void* const* d_in, const int* in_sizes, int n_in,
                              void* d_out, int out_size, void* d_ws, size_t ws_size,
                              hipStream_t stream) {
    const float* X    = (const float*)d_in[0];
    const float* W    = (const float*)d_in[1];
    const float* bias = (const float*)d_in[2];
    const int*   seg  = (const int*)d_in[3];
    float* out = (float*)d_out;

    ushort* Xb    = (ushort*)d_ws;                         // [32][12288] bf16, 0.75 MB
    float*  xpart = (float*)(Xb + (size_t)BATCH * KDIM);   // [KSPLIT][32][12288]

    convert_x_kernel<<<BATCH * KDIM / (256 * 4), 256, 0, stream>>>(X, Xb);

    const size_t base_ws = (size_t)BATCH * KDIM * 2;
    const size_t part_ws = (size_t)BATCH * DDIM * 4;
    if (ws_size >= base_ws + 8 * part_ws) {
        // grid 192*8 = 1536 = 3 x (2 blocks/CU x 256 CU)
        dim3 grid(DDIM / ROWS, 8);
        gemm_kernel<8><<<grid, 256, 0, stream>>>(W, Xb, xpart);
        aggregate_kernel<8><<<BATCH * CH, 256, 0, stream>>>(xpart, bias, seg, out);
    } else {
        dim3 grid(DDIM / ROWS, 4);
        gemm_kernel<4><<<grid, 256, 0, stream>>>(W, Xb, xpart);
        aggregate_kernel<4><<<BATCH * CH, 256, 0, stream>>>(xpart, bias, seg, out);
    }
}